// Round 10
// baseline (849.685 us; speedup 1.0000x reference)
//
#include <hip/hip_runtime.h>
#include <hip/hip_bf16.h>
#include <math.h>

#define N_NODES 50000
#define N_EDGES 800000
#define SCAN_B 196            // 196 blocks x 256 = 50176 >= N_NODES

typedef __hip_bfloat16 bf16;
typedef __attribute__((ext_vector_type(8))) short frag_ab;   // 8 bf16
typedef __attribute__((ext_vector_type(4))) float frag_cd;   // 4 f32
typedef __attribute__((ext_vector_type(2))) float f32x2;     // -> v_pk_fma_f32

__device__ __forceinline__ float b2f(bf16 v){ return __bfloat162float(v); }
__device__ __forceinline__ bf16 f2b(float v){ return __float2bfloat16(v); }
// decode 8 bf16 (uint4) -> 4 packed f32x2 pairs, channel pair j = (2j, 2j+1)
__device__ __forceinline__ void ld8dec2(uint4 u, f32x2* f){
    f[0] = (f32x2){__uint_as_float(u.x << 16), __uint_as_float(u.x & 0xFFFF0000u)};
    f[1] = (f32x2){__uint_as_float(u.y << 16), __uint_as_float(u.y & 0xFFFF0000u)};
    f[2] = (f32x2){__uint_as_float(u.z << 16), __uint_as_float(u.z & 0xFFFF0000u)};
    f[3] = (f32x2){__uint_as_float(u.w << 16), __uint_as_float(u.w & 0xFFFF0000u)};
}
__device__ __forceinline__ void ld8dec(uint4 u, float* f){
    f[0] = __uint_as_float(u.x << 16);
    f[1] = __uint_as_float(u.x & 0xFFFF0000u);
    f[2] = __uint_as_float(u.y << 16);
    f[3] = __uint_as_float(u.y & 0xFFFF0000u);
    f[4] = __uint_as_float(u.z << 16);
    f[5] = __uint_as_float(u.z & 0xFFFF0000u);
    f[6] = __uint_as_float(u.w << 16);
    f[7] = __uint_as_float(u.w & 0xFFFF0000u);
}
__device__ __forceinline__ unsigned pk2(float a, float b){
    return ((unsigned)__bfloat16_as_ushort(f2b(a))) |
           (((unsigned)__bfloat16_as_ushort(f2b(b))) << 16);
}
__device__ __forceinline__ float ldrt(const void* p, size_t i, bool f32){
    return f32 ? ((const float*)p)[i] : b2f(((const bf16*)p)[i]);
}
// async global->LDS, 16B per lane; LDS dest must be wave-uniform base + lane*16
__device__ __forceinline__ void gld16(const bf16* g, short* l){
    __builtin_amdgcn_global_load_lds(
        (const __attribute__((address_space(1))) void*)g,
        (__attribute__((address_space(3))) void*)l, 16, 0, 0);
}

// ---- fused: detect dtypes + convert 6 small vectors + zero degree bins -----
// flags[0] = edge_index is int64; flags[1] = float tensors are float32
__global__ __launch_bounds__(256) void detect_vec6(
    const int* __restrict__ ei, const unsigned int* __restrict__ xw,
    int* __restrict__ flags, int* __restrict__ dbin,
    const void* p0, const void* p1, const void* p2,
    const void* p3, const void* p4, const void* p5,
    float* __restrict__ outv){
    __shared__ int s64, sf32;
    const int t = threadIdx.x;
    if (t == 0){ s64 = 1; sf32 = 0; }
    __syncthreads();
    if (ei[2*t + 1] != 0) s64 = 0;                 // benign race: all write 0
    if (t < 64){
        unsigned int w = xw[t];
        float lo = __uint_as_float((w & 0xFFFFu) << 16);
        if (!(fabsf(lo) <= 64.f)) sf32 = 1;        // benign race
    }
    __syncthreads();
    if (t == 0){ flags[0] = s64; flags[1] = sf32; }
    dbin[t] = 0;
    const bool f32 = sf32 != 0;
    outv[0*256+t] = ldrt(p0, t, f32);
    outv[1*256+t] = ldrt(p1, t, f32);
    outv[2*256+t] = ldrt(p2, t, f32);
    outv[3*256+t] = ldrt(p3, t, f32);
    outv[4*256+t] = ldrt(p4, t, f32);
    outv[5*256+t] = ldrt(p5, t, f32);
}

// ---- convert x -> bf16 xb [N,128]; also zeroes counts (saves a dispatch) ---
__global__ __launch_bounds__(256) void conv_x(const void* __restrict__ xin,
                                              bf16* __restrict__ xb,
                                              int* __restrict__ counts,
                                              const int* __restrict__ flags){
    const int gid = blockIdx.x*256 + threadIdx.x;
    if (gid < N_NODES) counts[gid] = 0;
    const size_t i = (size_t)gid * 8;
    if (i >= (size_t)N_NODES*128) return;
    if (flags[1]){
        const float4* xf = (const float4*)((const float*)xin + i);
        const float4 x0 = xf[0], x1 = xf[1];
        uint4 o;
        o.x = pk2(x0.x, x0.y); o.y = pk2(x0.z, x0.w);
        o.z = pk2(x1.x, x1.y); o.w = pk2(x1.z, x1.w);
        *(uint4*)(xb + i) = o;
    } else {
        *(uint4*)(xb + i) = *(const uint4*)((const bf16*)xin + i);
    }
}

// ---- CSR build: histogram -> 3-phase parallel scan -> scatter --------------
__global__ __launch_bounds__(256) void hist_kernel(const int* __restrict__ ei,
                                                   int* __restrict__ counts,
                                                   const int* __restrict__ flags){
    const int e = blockIdx.x*256 + threadIdx.x;
    if (e >= N_EDGES) return;
    const bool i64 = flags[0] != 0;
    const int dst = i64 ? ((const int2*)ei)[N_EDGES + e].x : ei[N_EDGES + e];
    if ((unsigned)dst >= N_NODES) return;
    atomicAdd(&counts[dst], 1);
}

__global__ __launch_bounds__(256) void scan_phase1(const int* __restrict__ counts,
                                                   int* __restrict__ bsum){
    __shared__ int ws[4];
    const int idx = blockIdx.x*256 + threadIdx.x;
    int v = (idx < N_NODES) ? counts[idx] : 0;
    const int lane = threadIdx.x & 63, wid = threadIdx.x >> 6;
    #pragma unroll
    for (int off = 1; off < 64; off <<= 1) v += __shfl_xor(v, off, 64);
    if (lane == 0) ws[wid] = v;
    __syncthreads();
    if (threadIdx.x == 0) bsum[blockIdx.x] = ws[0]+ws[1]+ws[2]+ws[3];
}

__global__ __launch_bounds__(256) void scan_phase2(const int* __restrict__ bsum,
                                                   int* __restrict__ bbase){
    __shared__ int ws[4];
    const int t = threadIdx.x;
    const int lane = t & 63, wid = t >> 6;
    int v = (t < SCAN_B) ? bsum[t] : 0;
    int incl = v;
    #pragma unroll
    for (int off = 1; off < 64; off <<= 1){
        const int u = __shfl_up(incl, off, 64);
        if (lane >= off) incl += u;
    }
    if (lane == 63) ws[wid] = incl;
    __syncthreads();
    int wb = 0;
    for (int j = 0; j < wid; ++j) wb += ws[j];
    if (t < SCAN_B) bbase[t] = wb + incl - v;   // exclusive
}

// phase3 also histograms degrees (descending bins) for the node permutation
__global__ __launch_bounds__(256) void scan_phase3(const int* __restrict__ counts,
                                                   const int* __restrict__ bbase,
                                                   int* __restrict__ offsets,
                                                   int* __restrict__ cursor,
                                                   int* __restrict__ dbin){
    __shared__ int ws[4];
    const int idx = blockIdx.x*256 + threadIdx.x;
    const int lane = threadIdx.x & 63, wid = threadIdx.x >> 6;
    const int v = (idx < N_NODES) ? counts[idx] : 0;
    int incl = v;
    #pragma unroll
    for (int off = 1; off < 64; off <<= 1){
        const int u = __shfl_up(incl, off, 64);
        if (lane >= off) incl += u;
    }
    if (lane == 63) ws[wid] = incl;
    __syncthreads();
    int wb = bbase[blockIdx.x];
    for (int j = 0; j < wid; ++j) wb += ws[j];
    const int excl = wb + incl - v;
    if (idx < N_NODES){
        offsets[idx] = excl; cursor[idx] = excl;
        if (idx == N_NODES-1) offsets[N_NODES] = excl + v;
        atomicAdd(&dbin[255 - min(v, 255)], 1);   // descending-degree bins
    }
}

// exclusive scan of the 256 degree bins -> dcur (scatter cursors)
__global__ __launch_bounds__(256) void dscan(const int* __restrict__ dbin,
                                             int* __restrict__ dcur){
    __shared__ int ws[4];
    const int t = threadIdx.x;
    const int lane = t & 63, wid = t >> 6;
    const int v = dbin[t];
    int incl = v;
    #pragma unroll
    for (int off = 1; off < 64; off <<= 1){
        const int u = __shfl_up(incl, off, 64);
        if (lane >= off) incl += u;
    }
    if (lane == 63) ws[wid] = incl;
    __syncthreads();
    int wb = 0;
    for (int j = 0; j < wid; ++j) wb += ws[j];
    dcur[t] = wb + incl - v;
}

// scatter node ids into degree-sorted order[] (descending degree)
__global__ __launch_bounds__(256) void nscatter(const int* __restrict__ counts,
                                                int* __restrict__ dcur,
                                                int* __restrict__ order){
    const int idx = blockIdx.x*256 + threadIdx.x;
    if (idx >= N_NODES) return;
    const int bin = 255 - min(counts[idx], 255);
    const int pos = atomicAdd(&dcur[bin], 1);
    order[pos] = idx;
}

// edges[pos] = (src*1536 byte offset into P, eav bits)
__global__ __launch_bounds__(256) void scatter_kernel(
    const int* __restrict__ ei, const void* __restrict__ ea,
    int* __restrict__ cursor, int2* __restrict__ edges,
    const int* __restrict__ flags){
    const int e = blockIdx.x*256 + threadIdx.x;
    if (e >= N_EDGES) return;
    const bool i64 = flags[0] != 0, f32 = flags[1] != 0;
    const int src = i64 ? ((const int2*)ei)[e].x           : ei[e];
    const int dst = i64 ? ((const int2*)ei)[N_EDGES + e].x : ei[N_EDGES + e];
    if ((unsigned)src >= N_NODES || (unsigned)dst >= N_NODES) return;
    const float eav = f32 ? ((const float*)ea)[e] : b2f(((const bf16*)ea)[e]);
    const int pos = atomicAdd(&cursor[dst], 1);
    edges[pos] = make_int2(src * 1536, __float_as_int(eav));
}

// ---- transpose 8 weight mats (both layers) -> Wt bf16, biases -> f32 -------
// blockIdx.z = layer (0: K=128, 1: K=256); [K,256] -> Wt[1024][K]
__global__ __launch_bounds__(256) void trans_w_all(
    const void* w00, const void* w01, const void* w02, const void* w03,
    const void* b00, const void* b01, const void* b02, const void* b03,
    const void* w10, const void* w11, const void* w12, const void* w13,
    const void* b10, const void* b11, const void* b12, const void* b13,
    bf16* __restrict__ Wt0, float* __restrict__ bias0,
    bf16* __restrict__ Wt1, float* __restrict__ bias1,
    const int* __restrict__ flags)
{
    const bool f32 = flags[1] != 0;
    const int layer = blockIdx.z;
    const int K = layer ? 256 : 128;
    const int mi = blockIdx.y;
    const void* W; const void* B;
    if (layer == 0){
        W = mi==0?w00 : mi==1?w01 : mi==2?w02 : w03;
        B = mi==0?b00 : mi==1?b01 : mi==2?b02 : b03;
    } else {
        W = mi==0?w10 : mi==1?w11 : mi==2?w12 : w13;
        B = mi==0?b10 : mi==1?b11 : mi==2?b12 : b13;
    }
    bf16* Wt   = layer ? Wt1 : Wt0;
    float* bia = layer ? bias1 : bias0;
    const int t = threadIdx.x;
    if (blockIdx.x == 0) bia[mi*256 + t] = ldrt(B, t, f32);
    if (t >= K) return;
    const int c0 = blockIdx.x * 16;
    for (int c = c0; c < c0 + 16; ++c)
        Wt[(size_t)(mi*256 + c)*K + t] = f2b(ldrt(W, (size_t)t*256 + c, f32));
}

// ---- MFMA GEMM (128x128 tile, 4 waves, 4x4 MFMA tiles per wave) ------------
// m97 structure + T2 swizzle: global_load_lds width-16 into linear LDS
// [128][32]-short panels; GLOBAL source chunk pre-XOR-swizzled, frag ds_reads
// apply the same XOR -> max 2 lanes/bank (free).
// XCD-coherent 1D grid remap: d = 64*(M/8) + 8*n + (M%8) gives the 8 n-tiles
// of one A-panel dispatch indices == M (mod 8) -> same XCD under round-robin,
// within a 64-index window -> temporally adjacent. A-panel hits that L2 7/8.
// P[:, 0:768] = X@W(qkv)+b (row stride 768); cols 768..1023 -> skipb [N,256]
#define CST 132   // C-stage row stride in shorts (quads land on banks {0,8,16,24})
template<int K>
__global__ __launch_bounds__(256) void gemm_qkvs(
    const bf16* __restrict__ X, const bf16* __restrict__ Wt,
    const float* __restrict__ bias,
    bf16* __restrict__ P, bf16* __restrict__ skipb)
{
    const int d = blockIdx.x;
    const int M = (d >> 6) * 8 + (d & 7);      // m-panel 0..390
    const int n = (d >> 3) & 7;                 // n-tile 0..7
    if (M >= 391) return;

    __shared__ short smem[128*CST];    // 33792 B; K-loop uses first 16 KB
    short* As = smem;                  // [128][32] shorts, 8 KB
    short* Bs = smem + 4096;           // [128][32] shorts, 8 KB
    const int t = threadIdx.x;
    const int wave = t >> 6, lane = t & 63;
    const int quad = lane >> 4, l16 = lane & 15;
    const int wm = wave >> 1, wn = wave & 1;       // 2x2 wave grid
    const int m0 = M * 128;
    const int n0 = n * 128;

    // staging: thread t fills LDS row t>>2, chunk t&3 (8 shorts) from the
    // swizzled global chunk (t&3) ^ ((t>>3)&3)  [(row>>1)&3 with row = t>>2]
    const int r0 = t >> 2;              // 0..63 (row within 64-row half)
    const int cs = (((t & 3) ^ ((t >> 3) & 3)) * 8);
    const int ar0 = min(m0 + r0,      N_NODES-1);   // clamp tail (masked at store)
    const int ar1 = min(m0 + 64 + r0, N_NODES-1);
    const bf16* gA0 = X + (size_t)ar0*K + cs;
    const bf16* gA1 = X + (size_t)ar1*K + cs;
    const bf16* gB0 = Wt + (size_t)(n0 + r0)*K + cs;
    const bf16* gB1 = Wt + (size_t)(n0 + 64 + r0)*K + cs;
    short* lA = As + t*8;               // byte offset t*16
    short* lB = Bs + t*8;

    const int swz = (l16 >> 1) & 3;     // frag-read chunk XOR (row = ..+l16)

    frag_cd acc[4][4] = {};
    for (int k0 = 0; k0 < K; k0 += 32){
        if (k0) __syncthreads();        // prev frag reads done before overwrite
        gld16(gA0 + k0, lA);
        gld16(gA1 + k0, lA + 2048);     // +4 KB
        gld16(gB0 + k0, lB);
        gld16(gB1 + k0, lB + 2048);
        __syncthreads();                // drains vmcnt(0): LDS ready
        frag_ab af[4], bfm[4];
        #pragma unroll
        for (int i = 0; i < 4; ++i){
            af[i]  = *(const frag_ab*)&As[(wm*64 + i*16 + l16)*32 + ((quad ^ swz)*8)];
            bfm[i] = *(const frag_ab*)&Bs[(wn*64 + i*16 + l16)*32 + ((quad ^ swz)*8)];
        }
        #pragma unroll
        for (int mt = 0; mt < 4; ++mt)
            #pragma unroll
            for (int nt = 0; nt < 4; ++nt)
                acc[mt][nt] = __builtin_amdgcn_mfma_f32_16x16x32_bf16(
                    af[mt], bfm[nt], acc[mt][nt], 0, 0, 0);
    }

    // ---- epilogue: acc -> LDS (bias added) -> vectorized global stores ----
    __syncthreads();                    // K-loop ds_reads done before overwrite
    #pragma unroll
    for (int mt = 0; mt < 4; ++mt){
        #pragma unroll
        for (int nt = 0; nt < 4; ++nt){
            const int col = wn*64 + nt*16 + l16;
            const float bsum = bias[n0 + col];
            #pragma unroll
            for (int r = 0; r < 4; ++r){
                const int row = wm*64 + mt*16 + quad*4 + r;
                smem[row*CST + col] =
                    (short)__bfloat16_as_ushort(f2b(acc[mt][nt][r] + bsum));
            }
        }
    }
    __syncthreads();
    const bool toP = (n0 < 768);
    bf16* dstbase = toP ? (P + n0) : (skipb + (n0 - 768));
    const size_t rstride = toP ? 768 : 256;
    #pragma unroll
    for (int j = 0; j < 8; ++j){
        const int row = j*16 + (t >> 4);
        const int col = (t & 15) * 8;
        const int node = m0 + row;
        if (node < N_NODES){
            const uint4 val = *(const uint4*)&smem[row*CST + col];
            *(uint4*)(dstbase + (size_t)node*rstride + col) = val;
        }
    }
}

// ---- fused per-node attention + softmax + skip + LN (+ReLU) ----------------
// One wave per dst node (via degree-sorted order[] so the 4 nodes of a block
// have near-equal degree -> no retirement imbalance); wave split into 4
// groups of 16 lanes, each group processes one edge per iteration (4 edges
// in flight). Lane (g,l) owns channels l*16..l*16+15 of its group's edge.
// Inner math in f32x2 packed pairs -> v_pk_fma_f32.
// Algebra: q.(k+eav*ew) = q.k + eav*(q.ew);  sum a*(v+eav*ew) = sum a*v + ew*sum(a*eav)
template<int HEADS, bool RELU, bool OUTDYN>
__global__ __launch_bounds__(256) void node_attn(
    const bf16* __restrict__ P,          // [N,768] q|k|v
    const int2* __restrict__ edges,      // dst-sorted (src*1536, eav)
    const int* __restrict__ offsets,     // [N+1]
    const int* __restrict__ order,       // degree-sorted node permutation
    const bf16* __restrict__ skip,       // [N,256]
    const float* __restrict__ ewf,
    const float* __restrict__ gf, const float* __restrict__ bf_,
    void* __restrict__ out, const int* __restrict__ flags)
{
    const int idx = blockIdx.x*4 + (threadIdx.x >> 6);
    if (idx >= N_NODES) return;
    const int node = order[idx];
    const int lane = threadIdx.x & 63;
    const int g = lane >> 4;            // edge subgroup 0..3
    const int l = lane & 15;            // channel slice
    const float scale = (HEADS == 4) ? 0.125f : 0.0625f;
    const int RL = (HEADS == 4) ? 4 : 16;   // lanes per head within a group

    // q pairs for channels l*16..+15 (head = l>>2 when HEADS==4)
    const char* prow = (const char*)P + (size_t)node*1536;
    f32x2 q2[8];
    {
        uint4 qa = *(const uint4*)(prow + (l<<5));
        uint4 qb = *(const uint4*)(prow + (l<<5) + 16);
        ld8dec2(qa, q2); ld8dec2(qb, q2 + 4);
    }
    f32x2 ew2[8];
    {
        const float4* ep = (const float4*)(ewf + (l<<4));
        const float4 e0 = ep[0], e1 = ep[1], e2 = ep[2], e3 = ep[3];
        ew2[0] = (f32x2){e0.x, e0.y}; ew2[1] = (f32x2){e0.z, e0.w};
        ew2[2] = (f32x2){e1.x, e1.y}; ew2[3] = (f32x2){e1.z, e1.w};
        ew2[4] = (f32x2){e2.x, e2.y}; ew2[5] = (f32x2){e2.z, e2.w};
        ew2[6] = (f32x2){e3.x, e3.y}; ew2[7] = (f32x2){e3.z, e3.w};
    }
    // qew (per head): dot(q, ew) reduced over the head's lanes
    f32x2 qe2 = q2[0]*ew2[0];
    #pragma unroll
    for (int i = 1; i < 8; ++i) qe2 = q2[i]*ew2[i] + qe2;
    float qe = qe2.x + qe2.y;
    #pragma unroll
    for (int off = 1; off < RL; off <<= 1) qe += __shfl_xor(qe, off, 64);
    const float qewS = qe * scale;

    const int beg = offsets[node], end = offsets[node+1];
    float s = 0.f, seav = 0.f;
    f32x2 macc2[8];
    #pragma unroll
    for (int i = 0; i < 8; ++i) macc2[i] = (f32x2){0.f, 0.f};

    if (beg < end){
        const char* base = (const char*)P + (l << 5);
        const int nit = (end - beg + 3) >> 2;
        int e = beg + g;
        bool valid = e < end;
        int2 rec = edges[valid ? e : beg];
        const char* kp = base + (size_t)(unsigned)rec.x;
        uint4 k0 = *(const uint4*)(kp + 512);
        uint4 k1 = *(const uint4*)(kp + 528);
        uint4 v0 = *(const uint4*)(kp + 1024);
        uint4 v1 = *(const uint4*)(kp + 1040);
        for (int it = 0; it < nit; ++it){
            // ---- prefetch next edge for this group ----
            const int e2 = e + 4;
            const bool valid2 = e2 < end;
            const int2 rec2 = edges[valid2 ? e2 : beg];
            const char* kp2 = base + (size_t)(unsigned)rec2.x;
            const uint4 k0n = *(const uint4*)(kp2 + 512);
            const uint4 k1n = *(const uint4*)(kp2 + 528);
            const uint4 v0n = *(const uint4*)(kp2 + 1024);
            const uint4 v1n = *(const uint4*)(kp2 + 1040);
            // ---- current edge ----
            f32x2 kf[8];
            ld8dec2(k0, kf); ld8dec2(k1, kf + 4);
            f32x2 dp2 = q2[0]*kf[0];
            #pragma unroll
            for (int i = 1; i < 8; ++i) dp2 = q2[i]*kf[i] + dp2;
            float dp = dp2.x + dp2.y;
            #pragma unroll
            for (int off = 1; off < RL; off <<= 1) dp += __shfl_xor(dp, off, 64);
            const float eav = __int_as_float(rec.y);
            const float a = valid
                ? __expf(fminf(fmaf(dp, scale, eav*qewS), 80.f)) : 0.f;
            s += a;
            seav = fmaf(a, eav, seav);
            const f32x2 a2 = (f32x2){a, a};
            f32x2 vf[8];
            ld8dec2(v0, vf); ld8dec2(v1, vf + 4);
            #pragma unroll
            for (int i = 0; i < 8; ++i) macc2[i] = a2*vf[i] + macc2[i];
            // rotate pipeline
            e = e2; valid = valid2; rec = rec2;
            k0 = k0n; k1 = k1n; v0 = v0n; v1 = v1n;
        }
    }

    // cross-group combine (groups are 16 lanes apart)
    #pragma unroll
    for (int off = 16; off < 64; off <<= 1){
        s    += __shfl_xor(s, off, 64);
        seav += __shfl_xor(seav, off, 64);
        #pragma unroll
        for (int i = 0; i < 8; ++i){
            macc2[i].x += __shfl_xor(macc2[i].x, off, 64);
            macc2[i].y += __shfl_xor(macc2[i].y, off, 64);
        }
    }
    if (g != 0) return;     // group 0 finalizes the node

    float macc[16];
    #pragma unroll
    for (int i = 0; i < 8; ++i){ macc[2*i] = macc2[i].x; macc[2*i+1] = macc2[i].y; }

    const float rdenom = 1.f / (s + 1e-16f);
    float ewt[16];
    #pragma unroll
    for (int i = 0; i < 8; ++i){ ewt[2*i] = ew2[i].x; ewt[2*i+1] = ew2[i].y; }
    float sk[16];
    {
        const char* sp = (const char*)skip + (size_t)node*512 + (l<<5);
        uint4 sa = *(const uint4*)sp;
        uint4 sb = *(const uint4*)(sp + 16);
        ld8dec(sa, sk); ld8dec(sb, sk + 8);
    }
    float val[16];
    #pragma unroll
    for (int i = 0; i < 16; ++i)
        val[i] = fmaf(ewt[i], seav, macc[i]) * rdenom + sk[i];

    float sum = 0.f;
    #pragma unroll
    for (int i = 0; i < 16; ++i) sum += val[i];
    #pragma unroll
    for (int off = 1; off < 16; off <<= 1) sum += __shfl_xor(sum, off, 64);
    const float mu = sum * (1.f/256.f);
    float vs = 0.f;
    #pragma unroll
    for (int i = 0; i < 16; ++i){ const float d = val[i]-mu; vs = fmaf(d, d, vs); }
    #pragma unroll
    for (int off = 1; off < 16; off <<= 1) vs += __shfl_xor(vs, off, 64);
    const float rstd = rsqrtf(vs * (1.f/256.f) + 1e-5f);

    float ga[16], bb[16];
    {
        const float4* gp = (const float4*)(gf + (l<<4));
        const float4* bp = (const float4*)(bf_ + (l<<4));
        float4 g0 = gp[0], g1 = gp[1], g2 = gp[2], g3 = gp[3];
        float4 b0 = bp[0], b1 = bp[1], b2 = bp[2], b3 = bp[3];
        ga[0]=g0.x; ga[1]=g0.y; ga[2]=g0.z; ga[3]=g0.w;
        ga[4]=g1.x; ga[5]=g1.y; ga[6]=g1.z; ga[7]=g1.w;
        ga[8]=g2.x; ga[9]=g2.y; ga[10]=g2.z; ga[11]=g2.w;
        ga[12]=g3.x; ga[13]=g3.y; ga[14]=g3.z; ga[15]=g3.w;
        bb[0]=b0.x; bb[1]=b0.y; bb[2]=b0.z; bb[3]=b0.w;
        bb[4]=b1.x; bb[5]=b1.y; bb[6]=b1.z; bb[7]=b1.w;
        bb[8]=b2.x; bb[9]=b2.y; bb[10]=b2.z; bb[11]=b2.w;
        bb[12]=b3.x; bb[13]=b3.y; bb[14]=b3.z; bb[15]=b3.w;
    }
    float y[16];
    #pragma unroll
    for (int i = 0; i < 16; ++i){
        y[i] = (val[i]-mu) * rstd * ga[i] + bb[i];
        if (RELU) y[i] = fmaxf(y[i], 0.f);
    }
    const bool of32 = OUTDYN && (flags[1] != 0);
    if (of32){
        float* op = (float*)out + (size_t)node*256 + (l<<4);
        *(float4*)(op +  0) = make_float4(y[0],  y[1],  y[2],  y[3]);
        *(float4*)(op +  4) = make_float4(y[4],  y[5],  y[6],  y[7]);
        *(float4*)(op +  8) = make_float4(y[8],  y[9],  y[10], y[11]);
        *(float4*)(op + 12) = make_float4(y[12], y[13], y[14], y[15]);
    } else {
        bf16* op = (bf16*)out + (size_t)node*256 + (l<<4);
        uint4 o0, o1;
        o0.x = pk2(y[0],  y[1]);  o0.y = pk2(y[2],  y[3]);
        o0.z = pk2(y[4],  y[5]);  o0.w = pk2(y[6],  y[7]);
        o1.x = pk2(y[8],  y[9]);  o1.y = pk2(y[10], y[11]);
        o1.z = pk2(y[12], y[13]); o1.w = pk2(y[14], y[15]);
        *(uint4*)(op + 0) = o0;
        *(uint4*)(op + 8) = o1;
    }
}

extern "C" void kernel_launch(void* const* d_in, const int* in_sizes, int n_in,
                              void* d_out, int out_size, void* d_ws, size_t ws_size,
                              hipStream_t stream) {
    const int* ei = (const int*)d_in[1];

    // ---- workspace layout (bytes), peak ~110 MB ----
    char* w = (char*)d_ws;
    bf16*  P       = (bf16*) (w + 0);            // [N,768] (76.8MB)
    bf16*  xb      = (bf16*) (w + 76800000);     // [N,128] 12.8MB (dead after GEMM0)
    bf16*  Wt0     = (bf16*) (w + 89600000);     // 256KB, in gap; dead after GEMM0
    float* biasf0  = (float*)(w + 89862144);     // 4KB (region reborn as skipL1)
    bf16*  skipL1  = (bf16*) (w + 76800000);     // [N,256] 25.6MB (born at GEMM1)
    bf16*  Wt1     = (bf16*) (w + 102400000);    // 512KB (outlives skipL1 birth)
    float* biasf1  = (float*)(w + 102924288);    // 4KB
    int*   counts  = (int*)  (w + 102928384);    // 200KB
    int*   offsets = (int*)  (w + 103128384);    // 200KB+4
    int*   cursor  = (int*)  (w + 103328388);    // 200KB; dead after scatter ->
    int*   order   = (int*)  (w + 103328388);    //   reborn as order[] (nscatter)
    int2*  edges   = (int2*) (w + 103528392);    // 6.4MB
    float* vecs    = (float*)(w + 109928400);    // 6x256 f32
    int*   flags   = (int*)  (w + 109934544);
    int*   bsum    = (int*)  (w + 109934608);    // SCAN_B ints
    int*   bbase   = (int*)  (w + 109935392);    // SCAN_B ints
    int*   dbin    = (int*)  (w + 109936176);    // 256 ints (degree bins)
    int*   dcur    = (int*)  (w + 109937200);    // 256 ints (bin cursors)
    float* ewf0 = vecs + 0,   *ewf1 = vecs + 256;
    float* gf0  = vecs + 512, *bf0  = vecs + 768;
    float* gf1  = vecs + 1024,*bf1  = vecs + 1280;
    bf16*  skipL0 = (bf16*)d_out;   // d_out as scratch: skip -> h in-place
    bf16*  hbuf   = (bf16*)d_out;

    const int EB = (N_EDGES + 255) / 256;
    const int NB = (N_NODES + 3) / 4;
    const int GB = 3136;                // 49*64: XCD-coherent remap grid

    detect_vec6<<<1, 256, 0, stream>>>(ei, (const unsigned int*)d_in[0], flags,
                                       dbin,
                                       d_in[9], d_in[20], d_in[12], d_in[13],
                                       d_in[23], d_in[24], vecs);
    conv_x<<<3125, 256, 0, stream>>>(d_in[0], xb, counts, flags);
    // both layers' weight transposes in one launch, up-front
    trans_w_all<<<dim3(16,4,2), 256, 0, stream>>>(
        d_in[3], d_in[5], d_in[7], d_in[10],
        d_in[4], d_in[6], d_in[8], d_in[11],
        d_in[14], d_in[16], d_in[18], d_in[21],
        d_in[15], d_in[17], d_in[19], d_in[22],
        Wt0, biasf0, Wt1, biasf1, flags);
    // CSR build (once, shared by both layers)
    hist_kernel<<<EB, 256, 0, stream>>>(ei, counts, flags);
    scan_phase1<<<SCAN_B, 256, 0, stream>>>(counts, bsum);
    scan_phase2<<<1, 256, 0, stream>>>(bsum, bbase);
    scan_phase3<<<SCAN_B, 256, 0, stream>>>(counts, bbase, offsets, cursor, dbin);
    scatter_kernel<<<EB, 256, 0, stream>>>(ei, d_in[2], cursor, edges, flags);
    // degree-sorted node permutation (order reuses cursor region, now dead)
    dscan<<<1, 256, 0, stream>>>(dbin, dcur);
    nscatter<<<SCAN_B, 256, 0, stream>>>(counts, dcur, order);

    // ---------------- layer 0 ----------------
    gemm_qkvs<128><<<GB, 256, 0, stream>>>(xb, Wt0, biasf0, P, skipL0);
    node_attn<4, true, false><<<NB, 256, 0, stream>>>(
        P, edges, offsets, order, skipL0, ewf0, gf0, bf0, hbuf, flags);

    // ---------------- layer 1 ----------------
    gemm_qkvs<256><<<GB, 256, 0, stream>>>(hbuf, Wt1, biasf1, P, skipL1);
    node_attn<1, false, true><<<NB, 256, 0, stream>>>(
        P, edges, offsets, order, skipL1, ewf1, gf1, bf1, d_out, flags);
}

// Round 11
// 554.820 us; speedup vs baseline: 1.5315x; 1.5315x over previous
//
#include <hip/hip_runtime.h>
#include <hip/hip_bf16.h>
#include <math.h>

#define N_NODES 50000
#define N_EDGES 800000
#define SCAN_B 196            // 196 blocks x 256 = 50176 >= N_NODES

typedef __hip_bfloat16 bf16;
typedef __attribute__((ext_vector_type(8))) short frag_ab;   // 8 bf16
typedef __attribute__((ext_vector_type(4))) float frag_cd;   // 4 f32
typedef __attribute__((ext_vector_type(2))) float f32x2;     // -> v_pk_fma_f32

__device__ __forceinline__ float b2f(bf16 v){ return __bfloat162float(v); }
__device__ __forceinline__ bf16 f2b(float v){ return __float2bfloat16(v); }
// decode 8 bf16 (uint4) -> 4 packed f32x2 pairs, channel pair j = (2j, 2j+1)
__device__ __forceinline__ void ld8dec2(uint4 u, f32x2* f){
    f[0] = (f32x2){__uint_as_float(u.x << 16), __uint_as_float(u.x & 0xFFFF0000u)};
    f[1] = (f32x2){__uint_as_float(u.y << 16), __uint_as_float(u.y & 0xFFFF0000u)};
    f[2] = (f32x2){__uint_as_float(u.z << 16), __uint_as_float(u.z & 0xFFFF0000u)};
    f[3] = (f32x2){__uint_as_float(u.w << 16), __uint_as_float(u.w & 0xFFFF0000u)};
}
__device__ __forceinline__ void ld8dec(uint4 u, float* f){
    f[0] = __uint_as_float(u.x << 16);
    f[1] = __uint_as_float(u.x & 0xFFFF0000u);
    f[2] = __uint_as_float(u.y << 16);
    f[3] = __uint_as_float(u.y & 0xFFFF0000u);
    f[4] = __uint_as_float(u.z << 16);
    f[5] = __uint_as_float(u.z & 0xFFFF0000u);
    f[6] = __uint_as_float(u.w << 16);
    f[7] = __uint_as_float(u.w & 0xFFFF0000u);
}
__device__ __forceinline__ unsigned pk2(float a, float b){
    return ((unsigned)__bfloat16_as_ushort(f2b(a))) |
           (((unsigned)__bfloat16_as_ushort(f2b(b))) << 16);
}
__device__ __forceinline__ float ldrt(const void* p, size_t i, bool f32){
    return f32 ? ((const float*)p)[i] : b2f(((const bf16*)p)[i]);
}
// async global->LDS, 16B per lane; LDS dest must be wave-uniform base + lane*16
__device__ __forceinline__ void gld16(const bf16* g, short* l){
    __builtin_amdgcn_global_load_lds(
        (const __attribute__((address_space(1))) void*)g,
        (__attribute__((address_space(3))) void*)l, 16, 0, 0);
}

// ---- fused: detect dtypes + convert 6 small vectors (256 each) -> f32 ------
// flags[0] = edge_index is int64; flags[1] = float tensors are float32
__global__ __launch_bounds__(256) void detect_vec6(
    const int* __restrict__ ei, const unsigned int* __restrict__ xw,
    int* __restrict__ flags,
    const void* p0, const void* p1, const void* p2,
    const void* p3, const void* p4, const void* p5,
    float* __restrict__ outv){
    __shared__ int s64, sf32;
    const int t = threadIdx.x;
    if (t == 0){ s64 = 1; sf32 = 0; }
    __syncthreads();
    if (ei[2*t + 1] != 0) s64 = 0;                 // benign race: all write 0
    if (t < 64){
        unsigned int w = xw[t];
        float lo = __uint_as_float((w & 0xFFFFu) << 16);
        if (!(fabsf(lo) <= 64.f)) sf32 = 1;        // benign race
    }
    __syncthreads();
    if (t == 0){ flags[0] = s64; flags[1] = sf32; }
    const bool f32 = sf32 != 0;
    outv[0*256+t] = ldrt(p0, t, f32);
    outv[1*256+t] = ldrt(p1, t, f32);
    outv[2*256+t] = ldrt(p2, t, f32);
    outv[3*256+t] = ldrt(p3, t, f32);
    outv[4*256+t] = ldrt(p4, t, f32);
    outv[5*256+t] = ldrt(p5, t, f32);
}

// ---- convert x -> bf16 xb [N,128]; also zeroes counts (saves a dispatch) ---
__global__ __launch_bounds__(256) void conv_x(const void* __restrict__ xin,
                                              bf16* __restrict__ xb,
                                              int* __restrict__ counts,
                                              const int* __restrict__ flags){
    const int gid = blockIdx.x*256 + threadIdx.x;
    if (gid < N_NODES) counts[gid] = 0;
    const size_t i = (size_t)gid * 8;
    if (i >= (size_t)N_NODES*128) return;
    if (flags[1]){
        const float4* xf = (const float4*)((const float*)xin + i);
        const float4 x0 = xf[0], x1 = xf[1];
        uint4 o;
        o.x = pk2(x0.x, x0.y); o.y = pk2(x0.z, x0.w);
        o.z = pk2(x1.x, x1.y); o.w = pk2(x1.z, x1.w);
        *(uint4*)(xb + i) = o;
    } else {
        *(uint4*)(xb + i) = *(const uint4*)((const bf16*)xin + i);
    }
}

// ---- CSR build: histogram -> 3-phase parallel scan -> scatter --------------
__global__ __launch_bounds__(256) void hist_kernel(const int* __restrict__ ei,
                                                   int* __restrict__ counts,
                                                   const int* __restrict__ flags){
    const int e = blockIdx.x*256 + threadIdx.x;
    if (e >= N_EDGES) return;
    const bool i64 = flags[0] != 0;
    const int dst = i64 ? ((const int2*)ei)[N_EDGES + e].x : ei[N_EDGES + e];
    if ((unsigned)dst >= N_NODES) return;
    atomicAdd(&counts[dst], 1);
}

__global__ __launch_bounds__(256) void scan_phase1(const int* __restrict__ counts,
                                                   int* __restrict__ bsum){
    __shared__ int ws[4];
    const int idx = blockIdx.x*256 + threadIdx.x;
    int v = (idx < N_NODES) ? counts[idx] : 0;
    const int lane = threadIdx.x & 63, wid = threadIdx.x >> 6;
    #pragma unroll
    for (int off = 1; off < 64; off <<= 1) v += __shfl_xor(v, off, 64);
    if (lane == 0) ws[wid] = v;
    __syncthreads();
    if (threadIdx.x == 0) bsum[blockIdx.x] = ws[0]+ws[1]+ws[2]+ws[3];
}

__global__ __launch_bounds__(256) void scan_phase2(const int* __restrict__ bsum,
                                                   int* __restrict__ bbase){
    __shared__ int ws[4];
    const int t = threadIdx.x;
    const int lane = t & 63, wid = t >> 6;
    int v = (t < SCAN_B) ? bsum[t] : 0;
    int incl = v;
    #pragma unroll
    for (int off = 1; off < 64; off <<= 1){
        const int u = __shfl_up(incl, off, 64);
        if (lane >= off) incl += u;
    }
    if (lane == 63) ws[wid] = incl;
    __syncthreads();
    int wb = 0;
    for (int j = 0; j < wid; ++j) wb += ws[j];
    if (t < SCAN_B) bbase[t] = wb + incl - v;   // exclusive
}

__global__ __launch_bounds__(256) void scan_phase3(const int* __restrict__ counts,
                                                   const int* __restrict__ bbase,
                                                   int* __restrict__ offsets,
                                                   int* __restrict__ cursor){
    __shared__ int ws[4];
    const int idx = blockIdx.x*256 + threadIdx.x;
    const int lane = threadIdx.x & 63, wid = threadIdx.x >> 6;
    const int v = (idx < N_NODES) ? counts[idx] : 0;
    int incl = v;
    #pragma unroll
    for (int off = 1; off < 64; off <<= 1){
        const int u = __shfl_up(incl, off, 64);
        if (lane >= off) incl += u;
    }
    if (lane == 63) ws[wid] = incl;
    __syncthreads();
    int wb = bbase[blockIdx.x];
    for (int j = 0; j < wid; ++j) wb += ws[j];
    const int excl = wb + incl - v;
    if (idx < N_NODES){
        offsets[idx] = excl; cursor[idx] = excl;
        if (idx == N_NODES-1) offsets[N_NODES] = excl + v;
    }
}

// edges[pos] = (src*1536 byte offset into P, eav bits)
__global__ __launch_bounds__(256) void scatter_kernel(
    const int* __restrict__ ei, const void* __restrict__ ea,
    int* __restrict__ cursor, int2* __restrict__ edges,
    const int* __restrict__ flags){
    const int e = blockIdx.x*256 + threadIdx.x;
    if (e >= N_EDGES) return;
    const bool i64 = flags[0] != 0, f32 = flags[1] != 0;
    const int src = i64 ? ((const int2*)ei)[e].x           : ei[e];
    const int dst = i64 ? ((const int2*)ei)[N_EDGES + e].x : ei[N_EDGES + e];
    if ((unsigned)src >= N_NODES || (unsigned)dst >= N_NODES) return;
    const float eav = f32 ? ((const float*)ea)[e] : b2f(((const bf16*)ea)[e]);
    const int pos = atomicAdd(&cursor[dst], 1);
    edges[pos] = make_int2(src * 1536, __float_as_int(eav));
}

// ---- transpose 8 weight mats (both layers) -> Wt bf16, biases -> f32 -------
// blockIdx.z = layer (0: K=128, 1: K=256); [K,256] -> Wt[1024][K]
__global__ __launch_bounds__(256) void trans_w_all(
    const void* w00, const void* w01, const void* w02, const void* w03,
    const void* b00, const void* b01, const void* b02, const void* b03,
    const void* w10, const void* w11, const void* w12, const void* w13,
    const void* b10, const void* b11, const void* b12, const void* b13,
    bf16* __restrict__ Wt0, float* __restrict__ bias0,
    bf16* __restrict__ Wt1, float* __restrict__ bias1,
    const int* __restrict__ flags)
{
    const bool f32 = flags[1] != 0;
    const int layer = blockIdx.z;
    const int K = layer ? 256 : 128;
    const int mi = blockIdx.y;
    const void* W; const void* B;
    if (layer == 0){
        W = mi==0?w00 : mi==1?w01 : mi==2?w02 : w03;
        B = mi==0?b00 : mi==1?b01 : mi==2?b02 : b03;
    } else {
        W = mi==0?w10 : mi==1?w11 : mi==2?w12 : w13;
        B = mi==0?b10 : mi==1?b11 : mi==2?b12 : b13;
    }
    bf16* Wt   = layer ? Wt1 : Wt0;
    float* bia = layer ? bias1 : bias0;
    const int t = threadIdx.x;
    if (blockIdx.x == 0) bia[mi*256 + t] = ldrt(B, t, f32);
    if (t >= K) return;
    const int c0 = blockIdx.x * 16;
    for (int c = c0; c < c0 + 16; ++c)
        Wt[(size_t)(mi*256 + c)*K + t] = f2b(ldrt(W, (size_t)t*256 + c, f32));
}

// ---- MFMA GEMM (128x128 tile, 4 waves, 4x4 MFMA tiles per wave) ------------
// m97 structure + T2 swizzle: global_load_lds width-16 into linear LDS
// [128][32]-short panels; GLOBAL source chunk pre-XOR-swizzled, frag ds_reads
// apply the same XOR -> max 2 lanes/bank (free).
// XCD-coherent 1D grid remap: d = 64*(M/8) + 8*n + (M%8) gives the 8 n-tiles
// of one A-panel dispatch indices == M (mod 8) -> same XCD under round-robin,
// within a 64-index window -> temporally adjacent. A-panel hits that L2 7/8.
// P[:, 0:768] = X@W(qkv)+b (row stride 768); cols 768..1023 -> skipb [N,256]
#define CST 132   // C-stage row stride in shorts (quads land on banks {0,8,16,24})
template<int K>
__global__ __launch_bounds__(256) void gemm_qkvs(
    const bf16* __restrict__ X, const bf16* __restrict__ Wt,
    const float* __restrict__ bias,
    bf16* __restrict__ P, bf16* __restrict__ skipb)
{
    const int d = blockIdx.x;
    const int M = (d >> 6) * 8 + (d & 7);      // m-panel 0..390
    const int n = (d >> 3) & 7;                 // n-tile 0..7
    if (M >= 391) return;

    __shared__ short smem[128*CST];    // 33792 B; K-loop uses first 16 KB
    short* As = smem;                  // [128][32] shorts, 8 KB
    short* Bs = smem + 4096;           // [128][32] shorts, 8 KB
    const int t = threadIdx.x;
    const int wave = t >> 6, lane = t & 63;
    const int quad = lane >> 4, l16 = lane & 15;
    const int wm = wave >> 1, wn = wave & 1;       // 2x2 wave grid
    const int m0 = M * 128;
    const int n0 = n * 128;

    // staging: thread t fills LDS row t>>2, chunk t&3 (8 shorts) from the
    // swizzled global chunk (t&3) ^ ((t>>3)&3)  [(row>>1)&3 with row = t>>2]
    const int r0 = t >> 2;              // 0..63 (row within 64-row half)
    const int cs = (((t & 3) ^ ((t >> 3) & 3)) * 8);
    const int ar0 = min(m0 + r0,      N_NODES-1);   // clamp tail (masked at store)
    const int ar1 = min(m0 + 64 + r0, N_NODES-1);
    const bf16* gA0 = X + (size_t)ar0*K + cs;
    const bf16* gA1 = X + (size_t)ar1*K + cs;
    const bf16* gB0 = Wt + (size_t)(n0 + r0)*K + cs;
    const bf16* gB1 = Wt + (size_t)(n0 + 64 + r0)*K + cs;
    short* lA = As + t*8;               // byte offset t*16
    short* lB = Bs + t*8;

    const int swz = (l16 >> 1) & 3;     // frag-read chunk XOR (row = ..+l16)

    frag_cd acc[4][4] = {};
    for (int k0 = 0; k0 < K; k0 += 32){
        if (k0) __syncthreads();        // prev frag reads done before overwrite
        gld16(gA0 + k0, lA);
        gld16(gA1 + k0, lA + 2048);     // +4 KB
        gld16(gB0 + k0, lB);
        gld16(gB1 + k0, lB + 2048);
        __syncthreads();                // drains vmcnt(0): LDS ready
        frag_ab af[4], bfm[4];
        #pragma unroll
        for (int i = 0; i < 4; ++i){
            af[i]  = *(const frag_ab*)&As[(wm*64 + i*16 + l16)*32 + ((quad ^ swz)*8)];
            bfm[i] = *(const frag_ab*)&Bs[(wn*64 + i*16 + l16)*32 + ((quad ^ swz)*8)];
        }
        #pragma unroll
        for (int mt = 0; mt < 4; ++mt)
            #pragma unroll
            for (int nt = 0; nt < 4; ++nt)
                acc[mt][nt] = __builtin_amdgcn_mfma_f32_16x16x32_bf16(
                    af[mt], bfm[nt], acc[mt][nt], 0, 0, 0);
    }

    // ---- epilogue: acc -> LDS (bias added) -> vectorized global stores ----
    __syncthreads();                    // K-loop ds_reads done before overwrite
    #pragma unroll
    for (int mt = 0; mt < 4; ++mt){
        #pragma unroll
        for (int nt = 0; nt < 4; ++nt){
            const int col = wn*64 + nt*16 + l16;
            const float bsum = bias[n0 + col];
            #pragma unroll
            for (int r = 0; r < 4; ++r){
                const int row = wm*64 + mt*16 + quad*4 + r;
                smem[row*CST + col] =
                    (short)__bfloat16_as_ushort(f2b(acc[mt][nt][r] + bsum));
            }
        }
    }
    __syncthreads();
    const bool toP = (n0 < 768);
    bf16* dstbase = toP ? (P + n0) : (skipb + (n0 - 768));
    const size_t rstride = toP ? 768 : 256;
    #pragma unroll
    for (int j = 0; j < 8; ++j){
        const int row = j*16 + (t >> 4);
        const int col = (t & 15) * 8;
        const int node = m0 + row;
        if (node < N_NODES){
            const uint4 val = *(const uint4*)&smem[row*CST + col];
            *(uint4*)(dstbase + (size_t)node*rstride + col) = val;
        }
    }
}

// ---- fused per-node attention + softmax + skip + LN (+ReLU) ----------------
// One wave per dst node; wave split into 4 groups of 16 lanes, each group
// processes one edge per iteration (4 edges in flight). Lane (g,l) owns
// channels l*16..l*16+15 of its group's edge. Inner math in f32x2 packed
// pairs -> v_pk_fma_f32 halves the FMA instruction count.
// Algebra: q.(k+eav*ew) = q.k + eav*(q.ew);  sum a*(v+eav*ew) = sum a*v + ew*sum(a*eav)
template<int HEADS, bool RELU, bool OUTDYN>
__global__ __launch_bounds__(256) void node_attn(
    const bf16* __restrict__ P,          // [N,768] q|k|v
    const int2* __restrict__ edges,      // dst-sorted (src*1536, eav)
    const int* __restrict__ offsets,     // [N+1]
    const bf16* __restrict__ skip,       // [N,256]
    const float* __restrict__ ewf,
    const float* __restrict__ gf, const float* __restrict__ bf_,
    void* __restrict__ out, const int* __restrict__ flags)
{
    const int node = blockIdx.x*4 + (threadIdx.x >> 6);
    if (node >= N_NODES) return;
    const int lane = threadIdx.x & 63;
    const int g = lane >> 4;            // edge subgroup 0..3
    const int l = lane & 15;            // channel slice
    const float scale = (HEADS == 4) ? 0.125f : 0.0625f;
    const int RL = (HEADS == 4) ? 4 : 16;   // lanes per head within a group

    // q pairs for channels l*16..+15 (head = l>>2 when HEADS==4)
    const char* prow = (const char*)P + (size_t)node*1536;
    f32x2 q2[8];
    {
        uint4 qa = *(const uint4*)(prow + (l<<5));
        uint4 qb = *(const uint4*)(prow + (l<<5) + 16);
        ld8dec2(qa, q2); ld8dec2(qb, q2 + 4);
    }
    f32x2 ew2[8];
    {
        const float4* ep = (const float4*)(ewf + (l<<4));
        const float4 e0 = ep[0], e1 = ep[1], e2 = ep[2], e3 = ep[3];
        ew2[0] = (f32x2){e0.x, e0.y}; ew2[1] = (f32x2){e0.z, e0.w};
        ew2[2] = (f32x2){e1.x, e1.y}; ew2[3] = (f32x2){e1.z, e1.w};
        ew2[4] = (f32x2){e2.x, e2.y}; ew2[5] = (f32x2){e2.z, e2.w};
        ew2[6] = (f32x2){e3.x, e3.y}; ew2[7] = (f32x2){e3.z, e3.w};
    }
    // qew (per head): dot(q, ew) reduced over the head's lanes
    f32x2 qe2 = q2[0]*ew2[0];
    #pragma unroll
    for (int i = 1; i < 8; ++i) qe2 = q2[i]*ew2[i] + qe2;
    float qe = qe2.x + qe2.y;
    #pragma unroll
    for (int off = 1; off < RL; off <<= 1) qe += __shfl_xor(qe, off, 64);
    const float qewS = qe * scale;

    const int beg = offsets[node], end = offsets[node+1];
    float s = 0.f, seav = 0.f;
    f32x2 macc2[8];
    #pragma unroll
    for (int i = 0; i < 8; ++i) macc2[i] = (f32x2){0.f, 0.f};

    if (beg < end){
        const char* base = (const char*)P + (l << 5);
        const int nit = (end - beg + 3) >> 2;
        int e = beg + g;
        bool valid = e < end;
        int2 rec = edges[valid ? e : beg];
        const char* kp = base + (size_t)(unsigned)rec.x;
        uint4 k0 = *(const uint4*)(kp + 512);
        uint4 k1 = *(const uint4*)(kp + 528);
        uint4 v0 = *(const uint4*)(kp + 1024);
        uint4 v1 = *(const uint4*)(kp + 1040);
        for (int it = 0; it < nit; ++it){
            // ---- prefetch next edge for this group ----
            const int e2 = e + 4;
            const bool valid2 = e2 < end;
            const int2 rec2 = edges[valid2 ? e2 : beg];
            const char* kp2 = base + (size_t)(unsigned)rec2.x;
            const uint4 k0n = *(const uint4*)(kp2 + 512);
            const uint4 k1n = *(const uint4*)(kp2 + 528);
            const uint4 v0n = *(const uint4*)(kp2 + 1024);
            const uint4 v1n = *(const uint4*)(kp2 + 1040);
            // ---- current edge ----
            f32x2 kf[8];
            ld8dec2(k0, kf); ld8dec2(k1, kf + 4);
            f32x2 dp2 = q2[0]*kf[0];
            #pragma unroll
            for (int i = 1; i < 8; ++i) dp2 = q2[i]*kf[i] + dp2;
            float dp = dp2.x + dp2.y;
            #pragma unroll
            for (int off = 1; off < RL; off <<= 1) dp += __shfl_xor(dp, off, 64);
            const float eav = __int_as_float(rec.y);
            const float a = valid
                ? __expf(fminf(fmaf(dp, scale, eav*qewS), 80.f)) : 0.f;
            s += a;
            seav = fmaf(a, eav, seav);
            const f32x2 a2 = (f32x2){a, a};
            f32x2 vf[8];
            ld8dec2(v0, vf); ld8dec2(v1, vf + 4);
            #pragma unroll
            for (int i = 0; i < 8; ++i) macc2[i] = a2*vf[i] + macc2[i];
            // rotate pipeline
            e = e2; valid = valid2; rec = rec2;
            k0 = k0n; k1 = k1n; v0 = v0n; v1 = v1n;
        }
    }

    // cross-group combine (groups are 16 lanes apart)
    #pragma unroll
    for (int off = 16; off < 64; off <<= 1){
        s    += __shfl_xor(s, off, 64);
        seav += __shfl_xor(seav, off, 64);
        #pragma unroll
        for (int i = 0; i < 8; ++i){
            macc2[i].x += __shfl_xor(macc2[i].x, off, 64);
            macc2[i].y += __shfl_xor(macc2[i].y, off, 64);
        }
    }
    if (g != 0) return;     // group 0 finalizes the node

    float macc[16];
    #pragma unroll
    for (int i = 0; i < 8; ++i){ macc[2*i] = macc2[i].x; macc[2*i+1] = macc2[i].y; }

    const float rdenom = 1.f / (s + 1e-16f);
    float ewt[16];
    #pragma unroll
    for (int i = 0; i < 8; ++i){ ewt[2*i] = ew2[i].x; ewt[2*i+1] = ew2[i].y; }
    float sk[16];
    {
        const char* sp = (const char*)skip + (size_t)node*512 + (l<<5);
        uint4 sa = *(const uint4*)sp;
        uint4 sb = *(const uint4*)(sp + 16);
        ld8dec(sa, sk); ld8dec(sb, sk + 8);
    }
    float val[16];
    #pragma unroll
    for (int i = 0; i < 16; ++i)
        val[i] = fmaf(ewt[i], seav, macc[i]) * rdenom + sk[i];

    float sum = 0.f;
    #pragma unroll
    for (int i = 0; i < 16; ++i) sum += val[i];
    #pragma unroll
    for (int off = 1; off < 16; off <<= 1) sum += __shfl_xor(sum, off, 64);
    const float mu = sum * (1.f/256.f);
    float vs = 0.f;
    #pragma unroll
    for (int i = 0; i < 16; ++i){ const float d = val[i]-mu; vs = fmaf(d, d, vs); }
    #pragma unroll
    for (int off = 1; off < 16; off <<= 1) vs += __shfl_xor(vs, off, 64);
    const float rstd = rsqrtf(vs * (1.f/256.f) + 1e-5f);

    float ga[16], bb[16];
    {
        const float4* gp = (const float4*)(gf + (l<<4));
        const float4* bp = (const float4*)(bf_ + (l<<4));
        float4 g0 = gp[0], g1 = gp[1], g2 = gp[2], g3 = gp[3];
        float4 b0 = bp[0], b1 = bp[1], b2 = bp[2], b3 = bp[3];
        ga[0]=g0.x; ga[1]=g0.y; ga[2]=g0.z; ga[3]=g0.w;
        ga[4]=g1.x; ga[5]=g1.y; ga[6]=g1.z; ga[7]=g1.w;
        ga[8]=g2.x; ga[9]=g2.y; ga[10]=g2.z; ga[11]=g2.w;
        ga[12]=g3.x; ga[13]=g3.y; ga[14]=g3.z; ga[15]=g3.w;
        bb[0]=b0.x; bb[1]=b0.y; bb[2]=b0.z; bb[3]=b0.w;
        bb[4]=b1.x; bb[5]=b1.y; bb[6]=b1.z; bb[7]=b1.w;
        bb[8]=b2.x; bb[9]=b2.y; bb[10]=b2.z; bb[11]=b2.w;
        bb[12]=b3.x; bb[13]=b3.y; bb[14]=b3.z; bb[15]=b3.w;
    }
    float y[16];
    #pragma unroll
    for (int i = 0; i < 16; ++i){
        y[i] = (val[i]-mu) * rstd * ga[i] + bb[i];
        if (RELU) y[i] = fmaxf(y[i], 0.f);
    }
    const bool of32 = OUTDYN && (flags[1] != 0);
    if (of32){
        float* op = (float*)out + (size_t)node*256 + (l<<4);
        *(float4*)(op +  0) = make_float4(y[0],  y[1],  y[2],  y[3]);
        *(float4*)(op +  4) = make_float4(y[4],  y[5],  y[6],  y[7]);
        *(float4*)(op +  8) = make_float4(y[8],  y[9],  y[10], y[11]);
        *(float4*)(op + 12) = make_float4(y[12], y[13], y[14], y[15]);
    } else {
        bf16* op = (bf16*)out + (size_t)node*256 + (l<<4);
        uint4 o0, o1;
        o0.x = pk2(y[0],  y[1]);  o0.y = pk2(y[2],  y[3]);
        o0.z = pk2(y[4],  y[5]);  o0.w = pk2(y[6],  y[7]);
        o1.x = pk2(y[8],  y[9]);  o1.y = pk2(y[10], y[11]);
        o1.z = pk2(y[12], y[13]); o1.w = pk2(y[14], y[15]);
        *(uint4*)(op + 0) = o0;
        *(uint4*)(op + 8) = o1;
    }
}

extern "C" void kernel_launch(void* const* d_in, const int* in_sizes, int n_in,
                              void* d_out, int out_size, void* d_ws, size_t ws_size,
                              hipStream_t stream) {
    const int* ei = (const int*)d_in[1];

    // ---- workspace layout (bytes), peak ~110 MB ----
    char* w = (char*)d_ws;
    bf16*  P       = (bf16*) (w + 0);            // [N,768] (76.8MB)
    bf16*  xb      = (bf16*) (w + 76800000);     // [N,128] 12.8MB (dead after GEMM0)
    bf16*  Wt0     = (bf16*) (w + 89600000);     // 256KB, in gap; dead after GEMM0
    float* biasf0  = (float*)(w + 89862144);     // 4KB (region reborn as skipL1)
    bf16*  skipL1  = (bf16*) (w + 76800000);     // [N,256] 25.6MB (born at GEMM1)
    bf16*  Wt1     = (bf16*) (w + 102400000);    // 512KB (outlives skipL1 birth)
    float* biasf1  = (float*)(w + 102924288);    // 4KB
    int*   counts  = (int*)  (w + 102928384);    // 200KB
    int*   offsets = (int*)  (w + 103128384);    // 200KB+4
    int*   cursor  = (int*)  (w + 103328388);    // 200KB
    int2*  edges   = (int2*) (w + 103528392);    // 6.4MB
    float* vecs    = (float*)(w + 109928400);    // 6x256 f32
    int*   flags   = (int*)  (w + 109934544);
    int*   bsum    = (int*)  (w + 109934608);    // SCAN_B ints
    int*   bbase   = (int*)  (w + 109935392);    // SCAN_B ints
    float* ewf0 = vecs + 0,   *ewf1 = vecs + 256;
    float* gf0  = vecs + 512, *bf0  = vecs + 768;
    float* gf1  = vecs + 1024,*bf1  = vecs + 1280;
    bf16*  skipL0 = (bf16*)d_out;   // d_out as scratch: skip -> h in-place
    bf16*  hbuf   = (bf16*)d_out;

    const int EB = (N_EDGES + 255) / 256;
    const int NB = (N_NODES + 3) / 4;
    const int GB = 3136;                // 49*64: XCD-coherent remap grid

    detect_vec6<<<1, 256, 0, stream>>>(ei, (const unsigned int*)d_in[0], flags,
                                       d_in[9], d_in[20], d_in[12], d_in[13],
                                       d_in[23], d_in[24], vecs);
    conv_x<<<3125, 256, 0, stream>>>(d_in[0], xb, counts, flags);
    // both layers' weight transposes in one launch, up-front
    trans_w_all<<<dim3(16,4,2), 256, 0, stream>>>(
        d_in[3], d_in[5], d_in[7], d_in[10],
        d_in[4], d_in[6], d_in[8], d_in[11],
        d_in[14], d_in[16], d_in[18], d_in[21],
        d_in[15], d_in[17], d_in[19], d_in[22],
        Wt0, biasf0, Wt1, biasf1, flags);
    // CSR build (once, shared by both layers)
    hist_kernel<<<EB, 256, 0, stream>>>(ei, counts, flags);
    scan_phase1<<<SCAN_B, 256, 0, stream>>>(counts, bsum);
    scan_phase2<<<1, 256, 0, stream>>>(bsum, bbase);
    scan_phase3<<<SCAN_B, 256, 0, stream>>>(counts, bbase, offsets, cursor);
    scatter_kernel<<<EB, 256, 0, stream>>>(ei, d_in[2], cursor, edges, flags);

    // ---------------- layer 0 ----------------
    gemm_qkvs<128><<<GB, 256, 0, stream>>>(xb, Wt0, biasf0, P, skipL0);
    node_attn<4, true, false><<<NB, 256, 0, stream>>>(
        P, edges, offsets, skipL0, ewf0, gf0, bf0, hbuf, flags);

    // ---------------- layer 1 ----------------
    gemm_qkvs<256><<<GB, 256, 0, stream>>>(hbuf, Wt1, biasf1, P, skipL1);
    node_attn<1, false, true><<<NB, 256, 0, stream>>>(
        P, edges, offsets, skipL1, ewf1, gf1, bf1, d_out, flags);
}